// Round 11
// baseline (5700.148 us; speedup 1.0000x reference)
//
#include <hip/hip_runtime.h>
#include <hip/hip_bf16.h>

// SliceLSTM persistent kernel for gfx950, round 15: per-wave flag decoupling.
// Base = verified round-10 (4442us): 128 blocks x 256 thr (4 quarters x 32
// j-tiles, wave = gate), single bf16 act/h exchange planes via sc1/L3
// relaxed atomics, arrive/wait split flag barriers with gap-filled work.
// Round-15 delta (exchange protocol unchanged -- poll narrow, load wide once;
// tag-in-data is dead at every width, r11+r13):
//  * PER-WAVE flags. Wave g's acts are produced only by wave g (wave=gate)
//    and consumed only by wave g of other blocks, and vmcnt drains are
//    wave-scoped -- so each wave publishes its own flag after its own drain
//    and polls only the 32 flags it depends on (gate-g acts; 8x4 h flags).
//    Removes ALL barrier __syncthreads (5 -> 2 per step: only the gx LDS
//    exchange pair remains), removes wave0-poll serialization, and lets the
//    4 wave pipelines slide independently through barrier skew.

typedef unsigned short u16;
typedef unsigned long long u64;
typedef __attribute__((ext_vector_type(8))) short short8;
typedef __attribute__((ext_vector_type(4))) float floatx4;

#define NT 256
#define NBLK 128
#define TSTEPS 512

// ---- workspace layout (bytes) ----
#define WS_FLAG1 0                        // [4 q][4 g][32 jt] u32 = 2 KB
#define WS_FLAG2 2048                     // [4 q][32 jt][4 w] u32 = 2 KB
#define WS_H_HI 4096                      // 64 b x 512 j u16
#define WS_ZERO_BYTES (WS_H_HI + 65536)   // zeroed every call
#define WS_ACT_HI (WS_ZERO_BYTES)         // 2 planes x [4g][64b][512k] u16
#define ACT_PLANE 131072                  // elements per plane

__device__ __forceinline__ float b2f(u16 u) {
  unsigned v = ((unsigned)u) << 16;
  float f;
  __builtin_memcpy(&f, &v, 4);
  return f;
}
__device__ __forceinline__ u16 f2b(float f) {
  __hip_bfloat16 h = __float2bfloat16(f);  // RNE
  u16 u;
  __builtin_memcpy(&u, &h, 2);
  return u;
}
__device__ __forceinline__ float sigf(float x) { return 1.0f / (1.0f + __expf(-x)); }
__device__ __forceinline__ float tanhf_fast(float x) { return 2.0f * sigf(2.0f * x) - 1.0f; }
__device__ __forceinline__ short8 ld8(const u16* p) { return *(const short8*)p; }

// coherent 16B fragment load (sc1, straight from L3; relaxed -> batchable)
__device__ __forceinline__ short8 lda_frag(const u16* p) {
  union {
    u64 q[2];
    short8 s;
  } u;
  u.q[0] = __hip_atomic_load((const u64*)p, __ATOMIC_RELAXED, __HIP_MEMORY_SCOPE_AGENT);
  u.q[1] = __hip_atomic_load((const u64*)(p + 4), __ATOMIC_RELAXED, __HIP_MEMORY_SCOPE_AGENT);
  return u.s;
}
__device__ __forceinline__ void sta16(u16* p, u16 v) {
  __hip_atomic_store(p, v, __ATOMIC_RELAXED, __HIP_MEMORY_SCOPE_AGENT);
}
__device__ __forceinline__ void stflag(unsigned* p, unsigned v) {
  __hip_atomic_store(p, v, __ATOMIC_RELAXED, __HIP_MEMORY_SCOPE_AGENT);
}

__device__ __forceinline__ void split8v(float4 a, float4 b, short8& hi, short8& lo) {
  float v[8] = {a.x, a.y, a.z, a.w, b.x, b.y, b.z, b.w};
#pragma unroll
  for (int i = 0; i < 8; ++i) {
    u16 h = f2b(v[i]);
    hi[i] = (short)h;
    lo[i] = (short)f2b(v[i] - b2f(h));
  }
}

// Per-wave wait: every lane of the calling wave polls (fi duplicated across
// halves), ballot across 64 lanes. NO __syncthreads -- wave-scoped progress.
__device__ __forceinline__ void wave_wait(unsigned* flags, unsigned target) {
  const int fi = (int)(threadIdx.x & 31u);
  int spins = 0;
  for (;;) {
    const unsigned v =
        __hip_atomic_load(&flags[fi], __ATOMIC_RELAXED, __HIP_MEMORY_SCOPE_AGENT);
    if (__ballot(v >= target) == ~0ULL) break;
    if (++spins > (1 << 24)) break;  // watchdog -> fast wrong answer
    __builtin_amdgcn_s_sleep(1);
  }
}
// Per-wave arrive: drain THIS wave's stores (vmcnt is wave-scoped), publish.
__device__ __forceinline__ void wave_arrive(unsigned* flag, unsigned target) {
  asm volatile("s_waitcnt vmcnt(0)" ::: "memory");
  if ((threadIdx.x & 63u) == 0u) stflag(flag, target);
}

__global__ void __launch_bounds__(NT) init_ws_kernel(unsigned* w, int n) {
  int i = blockIdx.x * blockDim.x + threadIdx.x;
  const int st = gridDim.x * blockDim.x;
  for (; i < n; i += st) w[i] = 0u;
}

__global__ void __launch_bounds__(NT, 1) slicelstm_kernel(
    const float* __restrict__ x, const float* __restrict__ Ws,
    const float* __restrict__ Us, const float* __restrict__ biases,
    const float* __restrict__ Wc, const float* __restrict__ bcg,
    float* __restrict__ out, u16* __restrict__ act_hi, u16* __restrict__ h_hi,
    unsigned* __restrict__ flagbase) {
  __shared__ __align__(16) u16 W1H[64 * 200];  // [row=g*16+jj][k 0..191] +8 pad
  __shared__ __align__(16) u16 W2H[64 * 520];  // [row=g*16+jj][k 0..511] +8 pad
  __shared__ float gx[4][16][17];              // gate exchange, +1 pad

  const int tid = threadIdx.x;
  const int blk = blockIdx.x;
  const int q = blk & 3;    // batch quarter
  const int jt = blk >> 2;  // j-tile 0..31
  const int j0 = jt * 16;
  const int s = j0 >> 7;    // slice 0..3
  const int jbase = j0 & 127;

  // ---- one-time: split f32 weights, hi-planes -> LDS ----
  for (int i = tid; i < 64 * 192; i += NT) {
    const int r = i / 192, k = i % 192;
    const int col = (r >> 4) * 128 + jbase + (r & 15);
    const float w = (k < 64) ? Ws[(size_t)(s * 64 + k) * 512 + col]
                             : Us[(size_t)(s * 128 + (k - 64)) * 512 + col];
    W1H[r * 200 + k] = f2b(w);
  }
  for (int i = tid; i < 64 * 512; i += NT) {
    const int r = i >> 9, k = i & 511;
    const int col = (r >> 4) * 512 + j0 + (r & 15);
    W2H[r * 520 + k] = f2b(Wc[(size_t)k * 2048 + col]);
  }

  const int lane = tid & 63;
  const int g = tid >> 6;   // wave = gate
  const int lm = lane & 15;
  const int lq = lane >> 4;
  const int ko = lq * 8;

  // per-wave flag pointers
  unsigned* f1mine = flagbase + q * 128 + g * 32 + jt;   // my acts flag
  unsigned* f1poll = flagbase + q * 128 + g * 32;        // 32 gate-g flags
  unsigned* f2mine = flagbase + 512 + q * 128 + jt * 4 + g;  // my h flag
  unsigned* f2poll = flagbase + 512 + q * 128 + s * 32;      // 8 jt x 4 w flags

  // ---- one-time: lo-plane fragments -> VGPRs ----
  short8 w1l[6], w2l[16];
#pragma unroll
  for (int kt = 0; kt < 6; ++kt) {
    const int col = (g << 7) + jbase + lm;
#pragma unroll
    for (int e = 0; e < 8; ++e) {
      const int k = kt * 32 + ko + e;
      const float w = (k < 64) ? Ws[(size_t)(s * 64 + k) * 512 + col]
                               : Us[(size_t)(s * 128 + (k - 64)) * 512 + col];
      w1l[kt][e] = (short)f2b(w - b2f(f2b(w)));
    }
  }
#pragma unroll
  for (int kt = 0; kt < 16; ++kt) {
    const int col = (g << 9) + j0 + lm;
#pragma unroll
    for (int e = 0; e < 8; ++e) {
      const float w = Wc[(size_t)(kt * 32 + ko + e) * 2048 + col];
      w2l[kt][e] = (short)f2b(w - b2f(f2b(w)));
    }
  }
  const float biasv = biases[s * 512 + (g << 7) + jbase + lm];
  const float bcv = bcg[(g << 9) + j0 + lm];
  __syncthreads();

  const u16* w1r = &W1H[((g << 4) + lm) * 200];
  const u16* w2r = &W2H[((g << 4) + lm) * 520];
  const int brow = q * 16 + lm;
  const float* xrow = x + (size_t)brow * (512 * 256) + s * 64;
  const int hbase = brow * 512 + s * 128;
  const int arow_off = ((g << 6) + brow) * 512;

  // phase-3 mapping
  const int p3b = tid >> 4, p3j = tid & 15;
  const int p3ci = (q * 16 + p3b) * 512 + j0 + p3j;
  const size_t obase = (size_t)(q * 16 + p3b) * TSTEPS * 512 + j0 + p3j;
  float creg = 0.f, hprev = 0.f;

  // x prefetch registers for t=0
  float4 xa0, xb0, xa1, xb1;
  {
    const float* xp = xrow;
    xa0 = *(const float4*)(xp + ko);
    xb0 = *(const float4*)(xp + ko + 4);
    xa1 = *(const float4*)(xp + 32 + ko);
    xb1 = *(const float4*)(xp + 32 + ko + 4);
  }

  for (int t = 0; t < TSTEPS; ++t) {
    // ---- phase 1a: x-part of stage-1 (independent of h(t-1)) ----
    short8 xh[2], xl[2];
    split8v(xa0, xb0, xh[0], xl[0]);
    split8v(xa1, xb1, xh[1], xl[1]);
    floatx4 accA = {0.f, 0.f, 0.f, 0.f}, accB = {0.f, 0.f, 0.f, 0.f};
    floatx4 accC = {0.f, 0.f, 0.f, 0.f};
#pragma unroll
    for (int kt = 0; kt < 2; ++kt) {
      const short8 bh = ld8(w1r + kt * 32 + ko);
      accA = __builtin_amdgcn_mfma_f32_16x16x32_bf16(xh[kt], bh, accA, 0, 0, 0);
      accB = __builtin_amdgcn_mfma_f32_16x16x32_bf16(xl[kt], bh, accB, 0, 0, 0);
      accC = __builtin_amdgcn_mfma_f32_16x16x32_bf16(xh[kt], w1l[kt], accC, 0, 0, 0);
    }

    // ---- wait2 (per-wave): h(t-1) visibility; trivial at t=0 ----
    wave_wait(f2poll, (unsigned)t);

    // ---- phase 0b: h loads (L3, single plane), batched behind one drain ----
    short8 hh[4];
#pragma unroll
    for (int kt = 0; kt < 4; ++kt) hh[kt] = lda_frag(&h_hi[hbase + kt * 32 + ko]);
    asm volatile("s_waitcnt vmcnt(0)" ::: "memory");
    __builtin_amdgcn_sched_barrier(0);

    // ---- phase 1b: h-part; activation; act stores (hi plane only) ----
    {
#pragma unroll
      for (int kt = 0; kt < 4; ++kt) {
        const short8 bh = ld8(w1r + 64 + kt * 32 + ko);
        accA = __builtin_amdgcn_mfma_f32_16x16x32_bf16(hh[kt], bh, accA, 0, 0, 0);
        accC = __builtin_amdgcn_mfma_f32_16x16x32_bf16(hh[kt], w1l[2 + kt], accC, 0, 0, 0);
      }
      const int pp = (t & 1) * ACT_PLANE;
#pragma unroll
      for (int r = 0; r < 4; ++r) {
        const int b = q * 16 + lq * 4 + r;
        const float pre = accA[r] + accB[r] + accC[r] + biasv;
        const float a = (g == 2) ? tanhf_fast(pre) : sigf(pre);
        sta16(&act_hi[pp + ((g << 6) + b) * 512 + j0 + lm], f2b(a));
      }
    }
    // ---- arrive1 (per-wave); fill gap with out store + x(t+1) prefetch ----
    wave_arrive(f1mine, (unsigned)(t + 1));
    if (t > 0) __builtin_nontemporal_store(hprev, &out[obase + (size_t)(t - 1) * 512]);
    {
      const float* xp = xrow + (size_t)(t < TSTEPS - 1 ? (t + 1) : t) * 256;
      xa0 = *(const float4*)(xp + ko);
      xb0 = *(const float4*)(xp + ko + 4);
      xa1 = *(const float4*)(xp + 32 + ko);
      xb1 = *(const float4*)(xp + 32 + ko + 4);
    }
    __builtin_amdgcn_sched_barrier(0);  // pin issue before the wait loop
    wave_wait(f1poll, (unsigned)(t + 1));

    // ---- phase 2: act loads (one drain); connector GEMM ----
    short8 Ah[16];
    {
      const u16* ahp = act_hi + (t & 1) * ACT_PLANE + arow_off;
#pragma unroll
      for (int kt = 0; kt < 16; ++kt) Ah[kt] = lda_frag(ahp + kt * 32 + ko);
    }
    asm volatile("s_waitcnt vmcnt(0)" ::: "memory");
    __builtin_amdgcn_sched_barrier(0);
    floatx4 a2a = {0.f, 0.f, 0.f, 0.f}, a2b = {0.f, 0.f, 0.f, 0.f};
    floatx4 a2c = {0.f, 0.f, 0.f, 0.f}, a2d = {0.f, 0.f, 0.f, 0.f};
#pragma unroll
    for (int kt = 0; kt < 16; kt += 2) {
      const int kb0 = kt * 32 + ko, kb1 = kb0 + 32;
      const short8 Bh0 = ld8(w2r + kb0), Bh1 = ld8(w2r + kb1);
      a2a = __builtin_amdgcn_mfma_f32_16x16x32_bf16(Ah[kt], Bh0, a2a, 0, 0, 0);
      a2b = __builtin_amdgcn_mfma_f32_16x16x32_bf16(Ah[kt], w2l[kt], a2b, 0, 0, 0);
      a2c = __builtin_amdgcn_mfma_f32_16x16x32_bf16(Ah[kt + 1], Bh1, a2c, 0, 0, 0);
      a2d = __builtin_amdgcn_mfma_f32_16x16x32_bf16(Ah[kt + 1], w2l[kt + 1], a2d, 0, 0, 0);
    }
#pragma unroll
    for (int r = 0; r < 4; ++r)
      gx[g][lq * 4 + r][lm] = (a2a[r] + a2c[r]) + (a2b[r] + a2d[r]) + bcv;
    __syncthreads();  // gx produced by all waves

    // ---- phase 3: elementwise update; h store (hi plane only) ----
    {
      const float it = sigf(gx[0][p3b][p3j]);
      const float ft = sigf(gx[1][p3b][p3j]);
      const float gt = tanhf_fast(gx[2][p3b][p3j]);
      const float ot = sigf(gx[3][p3b][p3j]);
      const float cn = ft * creg + it * gt;
      creg = cn;
      const float h = ot * tanhf_fast(cn);
      hprev = h;
      if (t < TSTEPS - 1) {
        sta16(&h_hi[p3ci], f2b(h));
      } else {
        __builtin_nontemporal_store(h, &out[obase + (size_t)t * 512]);
        __builtin_nontemporal_store(h, &out[16777216 + p3ci]);
        __builtin_nontemporal_store(cn, &out[16777216 + 32768 + p3ci]);
      }
    }
    __syncthreads();  // gx consumed by all waves before next step overwrites

    // ---- arrive2 (per-wave): publish h(t); wait happens next iteration ----
    if (t < TSTEPS - 1) wave_arrive(f2mine, (unsigned)(t + 1));
  }
}

extern "C" void kernel_launch(void* const* d_in, const int* in_sizes, int n_in,
                              void* d_out, int out_size, void* d_ws, size_t ws_size,
                              hipStream_t stream) {
  const float* x = (const float*)d_in[0];
  const float* Ws = (const float*)d_in[1];
  const float* Us = (const float*)d_in[2];
  const float* biases = (const float*)d_in[3];
  const float* Wc = (const float*)d_in[4];
  const float* bc = (const float*)d_in[5];

  char* ws = (char*)d_ws;
  unsigned* flagbase = (unsigned*)(ws + WS_FLAG1);
  u16* h_hi = (u16*)(ws + WS_H_HI);
  u16* act_hi = (u16*)(ws + WS_ACT_HI);

  hipLaunchKernelGGL(init_ws_kernel, dim3(64), dim3(NT), 0, stream, (unsigned*)ws,
                     WS_ZERO_BYTES / 4);
  hipLaunchKernelGGL(slicelstm_kernel, dim3(NBLK), dim3(NT), 0, stream, x, Ws, Us,
                     biases, Wc, bc, (float*)d_out, act_hi, h_hi, flagbase);
}